// Round 10
// baseline (130.033 us; speedup 1.0000x reference)
//
#include <hip/hip_runtime.h>
#include <hip/hip_bf16.h>

// Problem constants (fixed by the reference setup)
constexpr int   kB    = 2048;    // rows in feats
constexpr int   kC    = 256;     // feature dim
constexpr int   kG    = 128;     // group size = topk * num_instances
constexpr int   kKg   = 128;     // number of label groups
constexpr float kEps  = 1e-6f;
constexpr float kInvT = 20.0f;   // 1/0.05

typedef short bf16x8 __attribute__((ext_vector_type(8)));   // 8 bf16 in 4 VGPRs
typedef float floatx4 __attribute__((ext_vector_type(4)));  // MFMA accumulator

__device__ __forceinline__ unsigned short bf16_rne(float x) {
    union { float f; unsigned int u; } c; c.f = x;
    unsigned int r = c.u + 0x7FFFu + ((c.u >> 16) & 1u);
    return (unsigned short)(r >> 16);
}

// Pack 8 fp32 -> 8 bf16 (RNE, identical algebra to the old convert kernel
// -> bitwise-identical tiles -> results unchanged).
__device__ __forceinline__ uint4 cvt8(float4 lo, float4 hi) {
    uint4 u;
    u.x = (unsigned)bf16_rne(lo.x) | ((unsigned)bf16_rne(lo.y) << 16);
    u.y = (unsigned)bf16_rne(lo.z) | ((unsigned)bf16_rne(lo.w) << 16);
    u.z = (unsigned)bf16_rne(hi.x) | ((unsigned)bf16_rne(hi.y) << 16);
    u.w = (unsigned)bf16_rne(hi.z) | ((unsigned)bf16_rne(hi.w) << 16);
    return u;
}

// Kernel 1 (R20): sim/min-max with FUSED fp32->bf16 staging.
// R19 post-mortem: total tracks sim + ~76 µs fixed window (256 MB harness
// fill ~42 µs + convert ~6 + finalize ~3 + ~20 µs launch gaps). Atomic
// removal bought only ~4 µs (sim ~39 µs). The 40 µs sim plateau survived
// 5 structural theories — this round banks deterministic window wins:
// the separate convert kernel (+its launch gap) is deleted by staging
// straight from fp32 inputs with in-register RNE conversion. Same
// 128x128 tile, 2x2 waves of 64x64, XOR-swizzled LDS (R13/R18 core).
// Epilogue: plain stores to maxv[group][row] + pos_e (no atomics).
// Retired levers (do NOT reintroduce):
//  - atomicAdd to neg_e: WRITE_SIZE scales w/ atomic count; ~4 µs cost.
//  - static LDS > 128 KiB: launch fails on this harness (R11, R14).
//  - 256x256 / persistent-B / deep-vmcnt / barrier-free restructures:
//    all 40-58 µs, MfmaUtil 10-14% (R12/R13/R15/R16/R17).
//  - per-kk register prefetch inside the MFMA loop: spills (R5/R8/R9).
//  - permuted-lane LDS dest for global_load_lds: breaks DMA (R4).
//  - fused finalize w/ per-block __threadfence: +120 µs (R10).
__global__ __launch_bounds__(256) void sim_minmax_kernel(
    const float* __restrict__ feats,     // [2048,256] fp32
    const float* __restrict__ feats_s,   // [16384,256] fp32
    const int* __restrict__ labels,      // [2048]
    const int* __restrict__ labels_s,    // [16384]
    float* __restrict__ pos_e,           // [2048]
    float* __restrict__ maxv)            // [128][2048] block-max
{
    const int group = blockIdx.x;        // 0..127
    const int row0  = blockIdx.y * 128;  // 0..2047 step 128
    const int n0    = group * kG;        // base row in Fs / labels_s

    __shared__ alignas(16) __hip_bfloat16 As[128 * 64];
    __shared__ alignas(16) __hip_bfloat16 Bs[128 * 64];
    __shared__ float rmin[128][2];
    __shared__ float rmax[128][2];

    const int t    = threadIdx.x;
    const int wave = t >> 6;
    const int lane = t & 63;
    const int l15  = lane & 15;
    const int quad = lane >> 4;
    const int wm   = wave >> 1;   // row half (0..1)
    const int wn   = wave & 1;    // col half (0..1)

    floatx4 acc[4][4];
#pragma unroll
    for (int mt = 0; mt < 4; mt++)
#pragma unroll
        for (int nt = 0; nt < 4; nt++)
            acc[mt][nt] = (floatx4){0.f, 0.f, 0.f, 0.f};

    for (int k0 = 0; k0 < kC; k0 += 64) {
        // Stage A and B: 1024 bf16-16B chunks each (= 32B fp32 source);
        // c = t + 256*rep -> r = c>>3, q = c&7. Global fp32 reads
        // coalesced (8 lanes cover 256B contiguous); convert in-reg;
        // LDS write at swizzled p = q^(r&7).
#pragma unroll
        for (int rep = 0; rep < 4; rep++) {
            int c = t + 256 * rep, r = c >> 3, q = c & 7;
            int p = (q ^ (r & 7)) * 8;
            const float* ga = feats + (size_t)(row0 + r) * kC + k0 + q * 8;
            float4 a0 = *(const float4*)ga;
            float4 a1 = *(const float4*)(ga + 4);
            *(uint4*)(&As[r * 64 + p]) = cvt8(a0, a1);
            const float* gb = feats_s + (size_t)(n0 + r) * kC + k0 + q * 8;
            float4 b0 = *(const float4*)gb;
            float4 b1 = *(const float4*)(gb + 4);
            *(uint4*)(&Bs[r * 64 + p]) = cvt8(b0, b1);
        }
        __syncthreads();

#pragma unroll
        for (int kk = 0; kk < 64; kk += 32) {
            const int kc = kk >> 3;                        // logical chunk base 0 or 4
            const int pc = ((kc + quad) ^ (l15 & 7)) * 8;  // swizzled offset
            bf16x8 a[4], b[4];
#pragma unroll
            for (int mt = 0; mt < 4; mt++)
                a[mt] = *(const bf16x8*)(&As[(wm * 64 + mt * 16 + l15) * 64 + pc]);
#pragma unroll
            for (int nt = 0; nt < 4; nt++)
                b[nt] = *(const bf16x8*)(&Bs[(wn * 64 + nt * 16 + l15) * 64 + pc]);
#pragma unroll
            for (int mt = 0; mt < 4; mt++)
#pragma unroll
                for (int nt = 0; nt < 4; nt++)
                    acc[mt][nt] = __builtin_amdgcn_mfma_f32_16x16x32_bf16(
                        a[mt], b[nt], acc[mt][nt], 0, 0, 0);
        }
        __syncthreads();
    }

    // Per-row min/max over this wave's 64 columns.
    // D layout: col = lane&15, row = quad*4 + reg within each 16x16 tile.
#pragma unroll
    for (int mt = 0; mt < 4; mt++) {
#pragma unroll
        for (int reg = 0; reg < 4; reg++) {
            float vn = fminf(fminf(acc[mt][0][reg], acc[mt][1][reg]),
                             fminf(acc[mt][2][reg], acc[mt][3][reg]));
            float vx = fmaxf(fmaxf(acc[mt][0][reg], acc[mt][1][reg]),
                             fmaxf(acc[mt][2][reg], acc[mt][3][reg]));
#pragma unroll
            for (int s = 1; s < 16; s <<= 1) {
                vn = fminf(vn, __shfl_xor(vn, s, 64));
                vx = fmaxf(vx, __shfl_xor(vx, s, 64));
            }
            if (l15 == 0) {
                int r = wm * 64 + mt * 16 + quad * 4 + reg;
                rmin[r][wn] = vn;
                rmax[r][wn] = vx;
            }
        }
    }
    __syncthreads();

    if (t < 128) {
        float mn = fminf(rmin[t][0], rmin[t][1]);
        float mx = fmaxf(rmax[t][0], rmax[t][1]);
        int gb = row0 + t;
        // Plain coalesced stores, unique writer per slot. NO atomics.
        maxv[group * kB + gb] = mx;
        if (labels[gb] == labels_s[n0]) {
            pos_e[gb] = __expf(mn * kInvT);
        }
    }
}

// Kernel 2: per-row loss over the 128 group-maxes -> 8 block partials.
__global__ __launch_bounds__(256) void finalize1_kernel(
    const float* __restrict__ pos_e,     // [2048]
    const float* __restrict__ maxv,      // [128][2048]
    const int* __restrict__ labels,      // [2048]
    const int* __restrict__ labels_s,    // [16384]
    float* __restrict__ partial)         // [8]
{
    __shared__ int   gl[128];
    __shared__ float red[256];
    const int t = threadIdx.x;
    if (t < 128) gl[t] = labels_s[t * kG];
    __syncthreads();

    const int r   = blockIdx.x * 256 + t;
    const int lbl = labels[r];
    float s = 0.f, vpos = 0.f;
#pragma unroll 8
    for (int g = 0; g < kKg; g++) {
        float v = __expf(maxv[g * kB + r] * kInvT);
        s += v;
        if (gl[g] == lbl) vpos = v;
    }
    float p = pos_e[r];
    // neg_sum excludes the positive group's max (reference semantics).
    red[t] = -__logf(p / (p + (s - vpos) + kEps) + kEps);
    __syncthreads();
    for (int off = 128; off > 0; off >>= 1) {
        if (t < off) red[t] += red[t + off];
        __syncthreads();
    }
    if (t == 0) partial[blockIdx.x] = red[0];
}

// Kernel 3: sum 8 partials -> mean scalar.
__global__ void finalize2_kernel(const float* __restrict__ partial,
                                 float* __restrict__ out)
{
    if (threadIdx.x == 0) {
        float s = 0.f;
#pragma unroll
        for (int i = 0; i < 8; i++) s += partial[i];
        out[0] = s / (float)kB;
    }
}

extern "C" void kernel_launch(void* const* d_in, const int* in_sizes, int n_in,
                              void* d_out, int out_size, void* d_ws, size_t ws_size,
                              hipStream_t stream) {
    (void)in_sizes; (void)n_in; (void)out_size; (void)ws_size;

    const float* feats    = (const float*)d_in[0];
    const float* feats_s  = (const float*)d_in[1];
    const int*   labels   = (const int*)d_in[2];
    const int*   labels_s = (const int*)d_in[3];
    // d_in[4] = topk (8), d_in[5] = num_instances (16) — fixed, hard-coded.

    // ws layout: pos[2048] f32 | partial[8] f32 | pad to 32768 | maxv 1MB
    float* pos_e   = (float*)d_ws;
    float* partial = pos_e + kB;
    float* maxv    = (float*)((char*)d_ws + 32768);

    dim3 grid(kKg, kB / 128);   // 128 groups x 16 row-tiles = 2048 blocks
    sim_minmax_kernel<<<grid, 256, 0, stream>>>(
        feats, feats_s, labels, labels_s, pos_e, maxv);

    finalize1_kernel<<<kB / 256, 256, 0, stream>>>(
        pos_e, maxv, labels, labels_s, partial);
    finalize2_kernel<<<1, 64, 0, stream>>>(partial, (float*)d_out);
}

// Round 11
// 119.129 us; speedup vs baseline: 1.0915x; 1.0915x over previous
//
#include <hip/hip_runtime.h>
#include <hip/hip_bf16.h>

// Problem constants (fixed by the reference setup)
constexpr int   kB    = 2048;    // rows in feats
constexpr int   kC    = 256;     // feature dim
constexpr int   kG    = 128;     // group size = topk * num_instances
constexpr int   kKg   = 128;     // number of label groups
constexpr float kEps  = 1e-6f;
constexpr float kInvT = 20.0f;   // 1/0.05

constexpr int kNA = kB  * kC;    // 524288  feats elements
constexpr int kNB = kB * 8 * kC; // 4194304 feats_s elements

typedef short bf16x8 __attribute__((ext_vector_type(8)));   // 8 bf16 in 4 VGPRs
typedef float floatx4 __attribute__((ext_vector_type(4)));  // MFMA accumulator

__device__ __forceinline__ unsigned short bf16_rne(float x) {
    union { float f; unsigned int u; } c; c.f = x;
    unsigned int r = c.u + 0x7FFFu + ((c.u >> 16) & 1u);
    return (unsigned short)(r >> 16);
}

// Kernel 1: fp32 -> bf16 pre-convert (once). Separate kernel is load-
// bearing: fusing into sim staging costs +23 µs (R20: fp32 staging
// misses L3, FETCH 8.3->39 MB, VALUBusy 39%).
__global__ __launch_bounds__(256) void convert_kernel(
    const float* __restrict__ feats,    // [2048,256] fp32
    const float* __restrict__ feats_s,  // [16384,256] fp32
    __hip_bfloat16* __restrict__ fa,    // [2048,256] bf16 out
    __hip_bfloat16* __restrict__ fb)    // [16384,256] bf16 out
{
    int gid = blockIdx.x * 256 + threadIdx.x;
    size_t base = (size_t)gid * 8;
    const float* src; __hip_bfloat16* dst; size_t off;
    if (base < (size_t)kNA) { src = feats;   dst = fa; off = base; }
    else                    { src = feats_s; dst = fb; off = base - kNA; }
    float4 v0 = *(const float4*)(src + off);
    float4 v1 = *(const float4*)(src + off + 4);
    unsigned short u[8];
    u[0] = bf16_rne(v0.x); u[1] = bf16_rne(v0.y);
    u[2] = bf16_rne(v0.z); u[3] = bf16_rne(v0.w);
    u[4] = bf16_rne(v1.x); u[5] = bf16_rne(v1.y);
    u[6] = bf16_rne(v1.z); u[7] = bf16_rne(v1.w);
    *(uint4*)(dst + off) = *(const uint4*)u;
}

// Kernel 2 (R21 = R19 core with BK=32): 128x128 tile, 2x2 waves of
// 64x64, LDS cut 34.8 -> 17.4 KB to raise resident blocks/CU.
// Occupancy read ~23% (=2 blocks/CU) at every 34.8 KB variant despite
// nominal room for 4 — the one never-isolated axis. BK=32 guarantees
// >=4 blocks even with coarse LDS granularity; k0 steps double to 8.
// Swizzle at 4 granules/row: stage p = q^(r&3) (bijective per 1 KB,
// conflict-free writes); reads 4-way (accepted experiment cost).
// Epilogue: plain stores (no atomics), R18/R19-verified.
// Retired levers (do NOT reintroduce):
//  - fused fp32 staging: +23 µs (R20, FETCH 39 MB, L3 miss).
//  - atomicAdd to neg_e: ~4 µs memory-side cost (R18/R19).
//  - static LDS > 128 KiB: launch fails on this harness (R11, R14).
//  - 256x256 / persistent-B / deep-vmcnt / barrier-free restructures:
//    all 40-58 µs, MfmaUtil 10-14% (R12/R13/R15/R16/R17).
//  - per-kk register prefetch inside the MFMA loop: spills (R5/R8/R9).
//  - permuted-lane LDS dest for global_load_lds: breaks DMA (R4).
//  - fused finalize w/ per-block __threadfence: +120 µs (R10).
__global__ __launch_bounds__(256) void sim_minmax_kernel(
    const __hip_bfloat16* __restrict__ fa,   // [2048,256] bf16
    const __hip_bfloat16* __restrict__ fb,   // [16384,256] bf16
    const int* __restrict__ labels,          // [2048]
    const int* __restrict__ labels_s,        // [16384]
    float* __restrict__ pos_e,               // [2048]
    float* __restrict__ maxv)                // [128][2048] block-max
{
    const int group = blockIdx.x;        // 0..127
    const int row0  = blockIdx.y * 128;  // 0..2047 step 128
    const int n0    = group * kG;        // base row in Fs / labels_s

    __shared__ alignas(16) __hip_bfloat16 As[128 * 32];   // 8 KB
    __shared__ alignas(16) __hip_bfloat16 Bs[128 * 32];   // 8 KB
    __shared__ float rmin[128][2];
    __shared__ float rmax[128][2];
    // total 17.4 KB -> >=4 blocks/CU by LDS

    const int t    = threadIdx.x;
    const int wave = t >> 6;
    const int lane = t & 63;
    const int l15  = lane & 15;
    const int quad = lane >> 4;
    const int wm   = wave >> 1;   // row half (0..1)
    const int wn   = wave & 1;    // col half (0..1)

    floatx4 acc[4][4];
#pragma unroll
    for (int mt = 0; mt < 4; mt++)
#pragma unroll
        for (int nt = 0; nt < 4; nt++)
            acc[mt][nt] = (floatx4){0.f, 0.f, 0.f, 0.f};

    for (int k0 = 0; k0 < kC; k0 += 32) {
        // Stage A and B: 512 16B granules each; c = t + 256*rep ->
        // r = c>>2, q = c&3. Global reads coalesced (4 lanes = one
        // 64B line per row-slice); LDS write at swizzled p = q^(r&3)
        // (bijective within each 1 KB stripe -> conflict-free).
#pragma unroll
        for (int rep = 0; rep < 2; rep++) {
            int c = t + 256 * rep, r = c >> 2, q = c & 3;
            int p = (q ^ (r & 3)) * 8;
            uint4 va = *(const uint4*)(fa + (size_t)(row0 + r) * kC + k0 + q * 8);
            *(uint4*)(&As[r * 32 + p]) = va;
            uint4 vb = *(const uint4*)(fb + (size_t)(n0 + r) * kC + k0 + q * 8);
            *(uint4*)(&Bs[r * 32 + p]) = vb;
        }
        __syncthreads();

        {
            bf16x8 a[4], b[4];
#pragma unroll
            for (int mt = 0; mt < 4; mt++) {
                int rA = wm * 64 + mt * 16 + l15;
                a[mt] = *(const bf16x8*)(&As[rA * 32 + ((quad ^ (rA & 3)) * 8)]);
            }
#pragma unroll
            for (int nt = 0; nt < 4; nt++) {
                int rB = wn * 64 + nt * 16 + l15;
                b[nt] = *(const bf16x8*)(&Bs[rB * 32 + ((quad ^ (rB & 3)) * 8)]);
            }
#pragma unroll
            for (int mt = 0; mt < 4; mt++)
#pragma unroll
                for (int nt = 0; nt < 4; nt++)
                    acc[mt][nt] = __builtin_amdgcn_mfma_f32_16x16x32_bf16(
                        a[mt], b[nt], acc[mt][nt], 0, 0, 0);
        }
        __syncthreads();
    }

    // Per-row min/max over this wave's 64 columns.
    // D layout: col = lane&15, row = quad*4 + reg within each 16x16 tile.
#pragma unroll
    for (int mt = 0; mt < 4; mt++) {
#pragma unroll
        for (int reg = 0; reg < 4; reg++) {
            float vn = fminf(fminf(acc[mt][0][reg], acc[mt][1][reg]),
                             fminf(acc[mt][2][reg], acc[mt][3][reg]));
            float vx = fmaxf(fmaxf(acc[mt][0][reg], acc[mt][1][reg]),
                             fmaxf(acc[mt][2][reg], acc[mt][3][reg]));
#pragma unroll
            for (int s = 1; s < 16; s <<= 1) {
                vn = fminf(vn, __shfl_xor(vn, s, 64));
                vx = fmaxf(vx, __shfl_xor(vx, s, 64));
            }
            if (l15 == 0) {
                int r = wm * 64 + mt * 16 + quad * 4 + reg;
                rmin[r][wn] = vn;
                rmax[r][wn] = vx;
            }
        }
    }
    __syncthreads();

    if (t < 128) {
        float mn = fminf(rmin[t][0], rmin[t][1]);
        float mx = fmaxf(rmax[t][0], rmax[t][1]);
        int gb = row0 + t;
        // Plain coalesced stores, unique writer per slot. NO atomics.
        maxv[group * kB + gb] = mx;
        if (labels[gb] == labels_s[n0]) {
            pos_e[gb] = __expf(mn * kInvT);
        }
    }
}

// Kernel 3a: per-row loss over the 128 group-maxes -> 8 block partials.
__global__ __launch_bounds__(256) void finalize1_kernel(
    const float* __restrict__ pos_e,     // [2048]
    const float* __restrict__ maxv,      // [128][2048]
    const int* __restrict__ labels,      // [2048]
    const int* __restrict__ labels_s,    // [16384]
    float* __restrict__ partial)         // [8]
{
    __shared__ int   gl[128];
    __shared__ float red[256];
    const int t = threadIdx.x;
    if (t < 128) gl[t] = labels_s[t * kG];
    __syncthreads();

    const int r   = blockIdx.x * 256 + t;
    const int lbl = labels[r];
    float s = 0.f, vpos = 0.f;
#pragma unroll 8
    for (int g = 0; g < kKg; g++) {
        float v = __expf(maxv[g * kB + r] * kInvT);
        s += v;
        if (gl[g] == lbl) vpos = v;
    }
    float p = pos_e[r];
    // neg_sum excludes the positive group's max (reference semantics).
    red[t] = -__logf(p / (p + (s - vpos) + kEps) + kEps);
    __syncthreads();
    for (int off = 128; off > 0; off >>= 1) {
        if (t < off) red[t] += red[t + off];
        __syncthreads();
    }
    if (t == 0) partial[blockIdx.x] = red[0];
}

// Kernel 3b: sum 8 partials -> mean scalar.
__global__ void finalize2_kernel(const float* __restrict__ partial,
                                 float* __restrict__ out)
{
    if (threadIdx.x == 0) {
        float s = 0.f;
#pragma unroll
        for (int i = 0; i < 8; i++) s += partial[i];
        out[0] = s / (float)kB;
    }
}

extern "C" void kernel_launch(void* const* d_in, const int* in_sizes, int n_in,
                              void* d_out, int out_size, void* d_ws, size_t ws_size,
                              hipStream_t stream) {
    (void)in_sizes; (void)n_in; (void)out_size; (void)ws_size;

    const float* feats    = (const float*)d_in[0];
    const float* feats_s  = (const float*)d_in[1];
    const int*   labels   = (const int*)d_in[2];
    const int*   labels_s = (const int*)d_in[3];
    // d_in[4] = topk (8), d_in[5] = num_instances (16) — fixed, hard-coded.

    // ws layout: pos[2048] f32 | partial[8] f32 | pad to 32768 |
    //            fa 1MB | fb 8MB | maxv 1MB
    float* pos_e   = (float*)d_ws;
    float* partial = pos_e + kB;
    __hip_bfloat16* fa = (__hip_bfloat16*)((char*)d_ws + 32768);
    __hip_bfloat16* fb = (__hip_bfloat16*)((char*)d_ws + 32768 + (size_t)kNA * 2);
    float* maxv = (float*)((char*)d_ws + 32768 + (size_t)(kNA + kNB) * 2);

    // convert: (kNA + kNB)/8 threads = 589824 -> 2304 blocks of 256
    convert_kernel<<<(kNA + kNB) / 8 / 256, 256, 0, stream>>>(
        feats, feats_s, fa, fb);

    dim3 grid(kKg, kB / 128);   // 128 groups x 16 row-tiles = 2048 blocks
    sim_minmax_kernel<<<grid, 256, 0, stream>>>(
        fa, fb, labels, labels_s, pos_e, maxv);

    finalize1_kernel<<<kB / 256, 256, 0, stream>>>(
        pos_e, maxv, labels, labels_s, partial);
    finalize2_kernel<<<1, 64, 0, stream>>>(partial, (float*)d_out);
}